// Round 6
// baseline (1987.368 us; speedup 1.0000x reference)
//
#include <hip/hip_runtime.h>
#include <math.h>

#define BATCH 16
#define NTOK 1024
#define HEADS 8
#define DHEAD 64
#define INNER 512
#define QKV_COLS 1536
// 0.125 * log2(e): folded so p = exp2(qk*SCALE_L2E + bias*log2e)
#define SCALE_L2E 0.1803368801111244f
#define LOG2E 1.4426950408889634f

#if __has_builtin(__builtin_amdgcn_exp2f)
#define EXP2F(x) __builtin_amdgcn_exp2f(x)
#else
#define EXP2F(x) __expf((x) * 0.6931471805599453f)
#endif

typedef _Float16 f16x8 __attribute__((ext_vector_type(8)));
typedef _Float16 f16x4 __attribute__((ext_vector_type(4)));
typedef float f32x4 __attribute__((ext_vector_type(4)));

// async global->LDS, 16B per lane. LDS dest is wave-uniform base + lane*16.
__device__ __forceinline__ void glds16(const void* g, void* l) {
    __builtin_amdgcn_global_load_lds(
        (const __attribute__((address_space(1))) unsigned int*)g,
        (__attribute__((address_space(3))) unsigned int*)l, 16, 0, 0);
}

// ---------------------------------------------------------------------------
// Input conversion: x -> f16; W_qkv, W_out -> transposed f16 (Bt[n][k]).
// ---------------------------------------------------------------------------
#define XV (BATCH * NTOK * INNER / 4)        // 2097152 float4 groups
#define WQ (INNER * QKV_COLS)                // 786432
#define WO (INNER * INNER)                   // 262144

__global__ __launch_bounds__(256)
void convert_inputs(const float* __restrict__ x, const float* __restrict__ Wq,
                    const float* __restrict__ Wo, _Float16* __restrict__ x_h,
                    _Float16* __restrict__ Wq_t, _Float16* __restrict__ Wo_t) {
    int idx = blockIdx.x * 256 + threadIdx.x;
    if (idx < XV) {
        float4 v = ((const float4*)x)[idx];
        f16x4 h;
        h[0] = (_Float16)v.x; h[1] = (_Float16)v.y;
        h[2] = (_Float16)v.z; h[3] = (_Float16)v.w;
        *(f16x4*)(x_h + (size_t)idx * 4) = h;
    } else if (idx < XV + WQ) {
        int i = idx - XV;
        int n = i >> 9, k = i & 511;                 // Wq_t[n][k] = Wq[k][n]
        Wq_t[i] = (_Float16)Wq[k * QKV_COLS + n];
    } else if (idx < XV + WQ + WO) {
        int i = idx - XV - WQ;
        int n = i >> 9, k = i & 511;
        Wo_t[i] = (_Float16)Wo[k * INNER + n];
    }
}

// ---------------------------------------------------------------------------
// Bias materialization: biasT[h][j][i] = rel_table[relidx(i,j)][h] * log2e, f16.
// 8 * 1024 * 1024 f16 = 16 MB. One thread per 4 i's.
// ---------------------------------------------------------------------------
__global__ __launch_bounds__(256)
void build_bias(const float* __restrict__ rel_table, _Float16* __restrict__ biasT) {
    int gid = blockIdx.x * 256 + threadIdx.x;     // 2,097,152 threads
    int i4 = (gid & 255) * 4;
    int j  = (gid >> 8) & 1023;
    int h  = gid >> 18;
    int jy = j >> 5, jx = j & 31;
    f16x4 o;
#pragma unroll
    for (int r = 0; r < 4; ++r) {
        int i = i4 + r;
        int idx = ((i >> 5) - jy + 31) * 63 + ((i & 31) - jx + 31);
        o[r] = (_Float16)(rel_table[idx * HEADS + h] * LOG2E);
    }
    *(f16x4*)&biasT[((((size_t)h << 10) + j) << 10) + i4] = o;
}

// ---------------------------------------------------------------------------
// f16 MFMA GEMM (m97 structure): C[M,N] = A[M,K] @ Bt[N,K]^T  (+bias).
// ---------------------------------------------------------------------------
template<bool OUT_F16, bool ADD_BIAS>
__global__ __launch_bounds__(256)
void gemm_f16(const _Float16* __restrict__ A, const _Float16* __restrict__ Bt,
              const float* __restrict__ bias, void* __restrict__ Cout,
              int M, int N, int K) {
    __shared__ _Float16 As[128 * 32];
    __shared__ _Float16 Bs[128 * 32];

    const int t    = threadIdx.x;
    const int l    = t & 63;
    const int w    = t >> 6;
    const int wm   = w >> 1;
    const int wn   = w & 1;
    const int quad = l >> 4;
    const int lrow = l & 15;
    const size_t row0 = (size_t)blockIdx.y * 128;
    const size_t col0 = (size_t)blockIdx.x * 128;

    const int srow = t >> 2;
    const int sch  = t & 3;

    f32x4 acc[4][4] = {};

    for (int k0 = 0; k0 < K; k0 += 32) {
        __syncthreads();
        glds16(A + (row0 + srow) * K + k0 + sch * 8,            (char*)As + t * 16);
        glds16(A + (row0 + 64 + srow) * K + k0 + sch * 8,       (char*)As + 4096 + t * 16);
        glds16(Bt + (col0 + srow) * K + k0 + sch * 8,           (char*)Bs + t * 16);
        glds16(Bt + (col0 + 64 + srow) * K + k0 + sch * 8,      (char*)Bs + 4096 + t * 16);
        __syncthreads();

        f16x8 af[4], bf[4];
#pragma unroll
        for (int i = 0; i < 4; ++i)
            af[i] = *(const f16x8*)(As + (wm * 64 + i * 16 + lrow) * 32 + quad * 8);
#pragma unroll
        for (int j = 0; j < 4; ++j)
            bf[j] = *(const f16x8*)(Bs + (wn * 64 + j * 16 + lrow) * 32 + quad * 8);
#pragma unroll
        for (int i = 0; i < 4; ++i)
#pragma unroll
            for (int j = 0; j < 4; ++j)
                acc[i][j] = __builtin_amdgcn_mfma_f32_16x16x32_f16(af[i], bf[j], acc[i][j], 0, 0, 0);
    }

#pragma unroll
    for (int i = 0; i < 4; ++i) {
#pragma unroll
        for (int j = 0; j < 4; ++j) {
            size_t r = row0 + wm * 64 + i * 16 + quad * 4;
            size_t c = col0 + wn * 64 + j * 16 + lrow;
#pragma unroll
            for (int reg = 0; reg < 4; ++reg) {
                float v = acc[i][j][reg];
                if (OUT_F16) {
                    ((_Float16*)Cout)[(r + reg) * N + c] = (_Float16)v;
                } else {
                    if (ADD_BIAS) v += bias[c];
                    ((float*)Cout)[(r + reg) * N + c] = v;
                }
            }
        }
    }
}

// ---------------------------------------------------------------------------
// V pre-transpose: vt[b][h][d][n] = qkv[b*N+n][2*INNER + h*64 + d].
// ---------------------------------------------------------------------------
__global__ __launch_bounds__(256)
void transpose_v(const _Float16* __restrict__ qkv, _Float16* __restrict__ vt) {
    __shared__ _Float16 T[64][72];
    const int t  = threadIdx.x;
    const int j0 = blockIdx.x * 64;
    const int h  = blockIdx.y, bb = blockIdx.z;
    const int jr = t >> 2;
    const int dc = (t & 3) * 16;
    const _Float16* src = qkv + ((size_t)bb * NTOK + j0 + jr) * QKV_COLS + 2 * INNER + h * DHEAD + dc;
    f16x8 v0 = *(const f16x8*)src;
    f16x8 v1 = *(const f16x8*)(src + 8);
#pragma unroll
    for (int e = 0; e < 8; ++e) { T[jr][dc + e] = v0[e]; T[jr][dc + 8 + e] = v1[e]; }
    __syncthreads();
    const int dr = t >> 2;
    const int jc = (t & 3) * 16;
    f16x8 o0, o1;
#pragma unroll
    for (int e = 0; e < 8; ++e) { o0[e] = T[jc + e][dr]; o1[e] = T[jc + 8 + e][dr]; }
    _Float16* dst = vt + (((size_t)bb * HEADS + h) * 64 + dr) * NTOK + j0 + jc;
    *(f16x8*)dst = o0;
    *(f16x8*)(dst + 8) = o1;
}

// ---------------------------------------------------------------------------
// Flash attention v3: 128 Q rows/block, double-buffered async K/V staging,
// max-free exp2 softmax, bias from precomputed biasT via register-double-
// buffered global f16x4 loads. LDS = 48 KB -> 3 blocks/CU.
// Grid (8, HEADS, BATCH), 256 threads = 4 waves; each wave owns 32 Q rows.
// ---------------------------------------------------------------------------
__global__ __launch_bounds__(256, 3)
void attn_f16_v3(const _Float16* __restrict__ qkv, const _Float16* __restrict__ vt,
                 const _Float16* __restrict__ biasT, _Float16* __restrict__ out) {
    __shared__ _Float16 Ks[2][64 * 64];   // [j][d], swizzled chunks
    __shared__ _Float16 Vs[2][64 * 64];   // [d][j], swizzled chunks
    __shared__ _Float16 Ps[4][32 * 64];   // per-wave P[m][j], swizzled

    const int t    = threadIdx.x;
    const int l    = t & 63;
    const int w    = t >> 6;
    const int quad = l >> 4;
    const int lrow = l & 15;
    const int h    = blockIdx.y;
    const int bb   = blockIdx.z;
    const int i0   = blockIdx.x * 128;
    const int qr0  = i0 + w * 32;          // this wave's 32 query rows

    const size_t tokbase = (size_t)bb * NTOK;

    // Q fragments: A[m = lrow (+16*mt)][k = ksi*32 + quad*8 + e]
    f16x8 aq[2][2];
#pragma unroll
    for (int mt = 0; mt < 2; ++mt)
#pragma unroll
        for (int ksi = 0; ksi < 2; ++ksi)
            aq[mt][ksi] = *(const f16x8*)(qkv + (tokbase + qr0 + mt * 16 + lrow) * QKV_COLS
                                          + h * DHEAD + ksi * 32 + quad * 8);

    f32x4 O[2][4];
    float lpart[2][4];
#pragma unroll
    for (int mt = 0; mt < 2; ++mt)
#pragma unroll
        for (int k = 0; k < 4; ++k) {
            O[mt][k] = (f32x4){0.f, 0.f, 0.f, 0.f};
            lpart[mt][k] = 0.f;
        }

    const int kr  = t >> 3;     // staging row 0..31
    const int ksl = t & 7;      // LDS chunk slot; holds global chunk ksl^(row&7)
    const _Float16* kbase = qkv + tokbase * QKV_COLS + INNER + h * DHEAD;
    const _Float16* vbase = vt + ((size_t)(bb * HEADS + h) * 64) * NTOK;
    // bias rows j, cols i: this thread's i base = i0 + w*32 + mt*16 + quad*4
    const _Float16* bbase = biasT + ((size_t)h << 20) + i0 + w * 32 + quad * 4;

    auto stage = [&](int jt, int buf) {
        const int j0 = jt * 64;
        const int swz = (ksl ^ (kr & 7)) * 8;
        glds16(kbase + (size_t)(j0 + kr) * QKV_COLS + swz,      (char*)Ks[buf] + t * 16);
        glds16(kbase + (size_t)(j0 + 32 + kr) * QKV_COLS + swz, (char*)Ks[buf] + 4096 + t * 16);
        glds16(vbase + (size_t)kr * NTOK + j0 + swz,            (char*)Vs[buf] + t * 16);
        glds16(vbase + (size_t)(32 + kr) * NTOK + j0 + swz,     (char*)Vs[buf] + 4096 + t * 16);
    };

    f16x4 bfr[2][8];     // [buf][mt*4+jn], register double buffer
    auto load_bias = [&](int jt, int buf) {
#pragma unroll
        for (int mt = 0; mt < 2; ++mt)
#pragma unroll
            for (int jn = 0; jn < 4; ++jn)
                bfr[buf][mt * 4 + jn] =
                    *(const f16x4*)(bbase + (size_t)(jt * 64 + jn * 16 + lrow) * 1024 + mt * 16);
    };

    stage(0, 0);
    load_bias(0, 0);

    _Float16* Pw = Ps[w];

    for (int jt = 0; jt < 16; ++jt) {
        const int buf = jt & 1;
        __syncthreads();                 // staged tile jt ready; prev compute done
        if (jt < 15) { stage(jt + 1, buf ^ 1); load_bias(jt + 1, buf ^ 1); }

        // --- S = Q K^T ---
        f32x4 S[2][4];
#pragma unroll
        for (int jn = 0; jn < 4; ++jn) {
            S[0][jn] = (f32x4){0.f, 0.f, 0.f, 0.f};
            S[1][jn] = (f32x4){0.f, 0.f, 0.f, 0.f};
            const int row = jn * 16 + lrow;
#pragma unroll
            for (int ksi = 0; ksi < 2; ++ksi) {
                f16x8 bk = *(const f16x8*)(Ks[buf] + row * 64 + (((ksi * 4 + quad) ^ (row & 7)) * 8));
#pragma unroll
                for (int mt = 0; mt < 2; ++mt)
                    S[mt][jn] = __builtin_amdgcn_mfma_f32_16x16x32_f16(aq[mt][ksi], bk, S[mt][jn], 0, 0, 0);
            }
        }

        // --- p = exp2(qk*scale' + bias') ; partial sums; P write ---
#pragma unroll
        for (int jn = 0; jn < 4; ++jn) {
#pragma unroll
            for (int mt = 0; mt < 2; ++mt) {
                const int mbase = mt * 16 + quad * 4;
                const f16x4 bv4 = bfr[buf][mt * 4 + jn];
#pragma unroll
                for (int r = 0; r < 4; ++r) {
                    float p = EXP2F(fmaf(S[mt][jn][r], SCALE_L2E, (float)bv4[r]));
                    lpart[mt][r] += p;
                    const int mrow = mbase + r;
                    const int col  = jn * 16 + lrow;
                    Pw[mrow * 64 + (((col >> 3) ^ (mrow & 7)) * 8) + (col & 7)] = (_Float16)p;
                }
            }
        }
        asm volatile("" ::: "memory");   // same-wave DS write->read ordering

        // --- O += P @ V ---
#pragma unroll
        for (int ksi = 0; ksi < 2; ++ksi) {
            f16x8 ap[2];
#pragma unroll
            for (int mt = 0; mt < 2; ++mt) {
                const int arow = mt * 16 + lrow;
                ap[mt] = *(const f16x8*)(Pw + arow * 64 + (((ksi * 4 + quad) ^ (arow & 7)) * 8));
            }
#pragma unroll
            for (int dn = 0; dn < 4; ++dn) {
                const int d = dn * 16 + lrow;
                f16x8 bvv = *(const f16x8*)(Vs[buf] + d * 64 + (((ksi * 4 + quad) ^ (d & 7)) * 8));
#pragma unroll
                for (int mt = 0; mt < 2; ++mt)
                    O[mt][dn] = __builtin_amdgcn_mfma_f32_16x16x32_f16(ap[mt], bvv, O[mt][dn], 0, 0, 0);
            }
        }
    }

    // --- final l reduction across the 16 lanes holding each row, write out ---
#pragma unroll
    for (int mt = 0; mt < 2; ++mt) {
#pragma unroll
        for (int r = 0; r < 4; ++r) {
            float s = lpart[mt][r];
#pragma unroll
            for (int off = 1; off < 16; off <<= 1)
                s += __shfl_xor(s, off);
            float inv = 1.f / s;
            const int i = qr0 + mt * 16 + quad * 4 + r;
#pragma unroll
            for (int dn = 0; dn < 4; ++dn)
                out[(tokbase + i) * INNER + h * DHEAD + dn * 16 + lrow] =
                    (_Float16)(O[mt][dn][r] * inv);
        }
    }
}

// ---------------------------------------------------------------------------
extern "C" void kernel_launch(void* const* d_in, const int* in_sizes, int n_in,
                              void* d_out, int out_size, void* d_ws, size_t ws_size,
                              hipStream_t stream) {
    const float* x         = (const float*)d_in[0];
    const float* W_qkv     = (const float*)d_in[1];
    const float* rel_table = (const float*)d_in[2];
    const float* W_out     = (const float*)d_in[3];
    const float* b_out     = (const float*)d_in[4];

    _Float16* x_h   = (_Float16*)d_ws;                        // 8,388,608
    _Float16* Wq_t  = x_h + (size_t)BATCH * NTOK * INNER;     // 786,432
    _Float16* Wo_t  = Wq_t + (size_t)INNER * QKV_COLS;        // 262,144
    _Float16* qkv_h = Wo_t + (size_t)INNER * INNER;           // 25,165,824
    _Float16* att_h = qkv_h + (size_t)BATCH * NTOK * QKV_COLS;// 8,388,608
    _Float16* vt_g  = att_h + (size_t)BATCH * NTOK * INNER;   // 8,388,608
    _Float16* biasT = vt_g + (size_t)BATCH * NTOK * INNER;    // 8,388,608

    const int M = BATCH * NTOK;  // 16384

    build_bias<<<HEADS * NTOK * NTOK / 4 / 256, 256, 0, stream>>>(rel_table, biasT);

    convert_inputs<<<(XV + WQ + WO + 255) / 256, 256, 0, stream>>>(
        x, W_qkv, W_out, x_h, Wq_t, Wo_t);

    gemm_f16<true, false><<<dim3(QKV_COLS / 128, M / 128), 256, 0, stream>>>(
        x_h, Wq_t, nullptr, qkv_h, M, QKV_COLS, INNER);

    transpose_v<<<dim3(NTOK / 64, HEADS, BATCH), 256, 0, stream>>>(qkv_h, vt_g);

    attn_f16_v3<<<dim3(NTOK / 128, HEADS, BATCH), 256, 0, stream>>>(
        qkv_h, vt_g, biasT, att_h);

    gemm_f16<false, true><<<dim3(INNER / 128, M / 128), 256, 0, stream>>>(
        att_h, Wo_t, b_out, d_out, M, INNER, INNER);
}

// Round 10
// 276.357 us; speedup vs baseline: 7.1913x; 7.1913x over previous
//
#include <hip/hip_runtime.h>
#include <math.h>

#define BATCH 16
#define NTOK 1024
#define HEADS 8
#define DHEAD 64
#define INNER 512
#define QKV_COLS 1536
// 0.125 * log2(e): folded so p = exp2(qk*SCALE_L2E + bias*log2e)
#define SCALE_L2E 0.1803368801111244f
#define LOG2E 1.4426950408889634f

#if __has_builtin(__builtin_amdgcn_exp2f)
#define EXP2F(x) __builtin_amdgcn_exp2f(x)
#else
#define EXP2F(x) __expf((x) * 0.6931471805599453f)
#endif

typedef _Float16 f16x8 __attribute__((ext_vector_type(8)));
typedef _Float16 f16x4 __attribute__((ext_vector_type(4)));
typedef float f32x4 __attribute__((ext_vector_type(4)));

// async global->LDS, 16B per lane. LDS dest is wave-uniform base + lane*16.
__device__ __forceinline__ void glds16(const void* g, void* l) {
    __builtin_amdgcn_global_load_lds(
        (const __attribute__((address_space(1))) unsigned int*)g,
        (__attribute__((address_space(3))) unsigned int*)l, 16, 0, 0);
}

// ---------------------------------------------------------------------------
// Input conversion: x -> f16; W_qkv, W_out -> transposed f16 (Bt[n][k]).
// ---------------------------------------------------------------------------
#define XV (BATCH * NTOK * INNER / 4)        // 2097152 float4 groups
#define WQ (INNER * QKV_COLS)                // 786432
#define WO (INNER * INNER)                   // 262144

__global__ __launch_bounds__(256)
void convert_inputs(const float* __restrict__ x, const float* __restrict__ Wq,
                    const float* __restrict__ Wo, _Float16* __restrict__ x_h,
                    _Float16* __restrict__ Wq_t, _Float16* __restrict__ Wo_t) {
    int idx = blockIdx.x * 256 + threadIdx.x;
    if (idx < XV) {
        float4 v = ((const float4*)x)[idx];
        f16x4 h;
        h[0] = (_Float16)v.x; h[1] = (_Float16)v.y;
        h[2] = (_Float16)v.z; h[3] = (_Float16)v.w;
        *(f16x4*)(x_h + (size_t)idx * 4) = h;
    } else if (idx < XV + WQ) {
        int i = idx - XV;
        int n = i >> 9, k = i & 511;                 // Wq_t[n][k] = Wq[k][n]
        Wq_t[i] = (_Float16)Wq[k * QKV_COLS + n];
    } else if (idx < XV + WQ + WO) {
        int i = idx - XV - WQ;
        int n = i >> 9, k = i & 511;
        Wo_t[i] = (_Float16)Wo[k * INNER + n];
    }
}

// ---------------------------------------------------------------------------
// Bias materialization: biasT[h][j][i] = rel_table[relidx(i,j)][h] * log2e, f16.
// ---------------------------------------------------------------------------
__global__ __launch_bounds__(256)
void build_bias(const float* __restrict__ rel_table, _Float16* __restrict__ biasT) {
    int gid = blockIdx.x * 256 + threadIdx.x;     // 2,097,152 threads
    int i4 = (gid & 255) * 4;
    int j  = (gid >> 8) & 1023;
    int h  = gid >> 18;
    int jy = j >> 5, jx = j & 31;
    f16x4 o;
#pragma unroll
    for (int r = 0; r < 4; ++r) {
        int i = i4 + r;
        int idx = ((i >> 5) - jy + 31) * 63 + ((i & 31) - jx + 31);
        o[r] = (_Float16)(rel_table[idx * HEADS + h] * LOG2E);
    }
    *(f16x4*)&biasT[((((size_t)h << 10) + j) << 10) + i4] = o;
}

// ---------------------------------------------------------------------------
// f16 MFMA GEMM (m97 structure): C[M,N] = A[M,K] @ Bt[N,K]^T  (+bias).
// ---------------------------------------------------------------------------
template<bool OUT_F16, bool ADD_BIAS>
__global__ __launch_bounds__(256)
void gemm_f16(const _Float16* __restrict__ A, const _Float16* __restrict__ Bt,
              const float* __restrict__ bias, void* __restrict__ Cout,
              int M, int N, int K) {
    __shared__ _Float16 As[128 * 32];
    __shared__ _Float16 Bs[128 * 32];

    const int t    = threadIdx.x;
    const int l    = t & 63;
    const int w    = t >> 6;
    const int wm   = w >> 1;
    const int wn   = w & 1;
    const int quad = l >> 4;
    const int lrow = l & 15;
    const size_t row0 = (size_t)blockIdx.y * 128;
    const size_t col0 = (size_t)blockIdx.x * 128;

    const int srow = t >> 2;
    const int sch  = t & 3;

    f32x4 acc[4][4] = {};

    for (int k0 = 0; k0 < K; k0 += 32) {
        __syncthreads();
        glds16(A + (row0 + srow) * K + k0 + sch * 8,            (char*)As + t * 16);
        glds16(A + (row0 + 64 + srow) * K + k0 + sch * 8,       (char*)As + 4096 + t * 16);
        glds16(Bt + (col0 + srow) * K + k0 + sch * 8,           (char*)Bs + t * 16);
        glds16(Bt + (col0 + 64 + srow) * K + k0 + sch * 8,      (char*)Bs + 4096 + t * 16);
        __syncthreads();

        f16x8 af[4], bf[4];
#pragma unroll
        for (int i = 0; i < 4; ++i)
            af[i] = *(const f16x8*)(As + (wm * 64 + i * 16 + lrow) * 32 + quad * 8);
#pragma unroll
        for (int j = 0; j < 4; ++j)
            bf[j] = *(const f16x8*)(Bs + (wn * 64 + j * 16 + lrow) * 32 + quad * 8);
#pragma unroll
        for (int i = 0; i < 4; ++i)
#pragma unroll
            for (int j = 0; j < 4; ++j)
                acc[i][j] = __builtin_amdgcn_mfma_f32_16x16x32_f16(af[i], bf[j], acc[i][j], 0, 0, 0);
    }

#pragma unroll
    for (int i = 0; i < 4; ++i) {
#pragma unroll
        for (int j = 0; j < 4; ++j) {
            size_t r = row0 + wm * 64 + i * 16 + quad * 4;
            size_t c = col0 + wn * 64 + j * 16 + lrow;
#pragma unroll
            for (int reg = 0; reg < 4; ++reg) {
                float v = acc[i][j][reg];
                if (OUT_F16) {
                    ((_Float16*)Cout)[(r + reg) * N + c] = (_Float16)v;
                } else {
                    if (ADD_BIAS) v += bias[c];
                    ((float*)Cout)[(r + reg) * N + c] = v;
                }
            }
        }
    }
}

// ---------------------------------------------------------------------------
// V pre-transpose: vt[b][h][d][n] = qkv[b*N+n][2*INNER + h*64 + d].
// ---------------------------------------------------------------------------
__global__ __launch_bounds__(256)
void transpose_v(const _Float16* __restrict__ qkv, _Float16* __restrict__ vt) {
    __shared__ _Float16 T[64][72];
    const int t  = threadIdx.x;
    const int j0 = blockIdx.x * 64;
    const int h  = blockIdx.y, bb = blockIdx.z;
    const int jr = t >> 2;
    const int dc = (t & 3) * 16;
    const _Float16* src = qkv + ((size_t)bb * NTOK + j0 + jr) * QKV_COLS + 2 * INNER + h * DHEAD + dc;
    f16x8 v0 = *(const f16x8*)src;
    f16x8 v1 = *(const f16x8*)(src + 8);
#pragma unroll
    for (int e = 0; e < 8; ++e) { T[jr][dc + e] = v0[e]; T[jr][dc + 8 + e] = v1[e]; }
    __syncthreads();
    const int dr = t >> 2;
    const int jc = (t & 3) * 16;
    f16x8 o0, o1;
#pragma unroll
    for (int e = 0; e < 8; ++e) { o0[e] = T[jc + e][dr]; o1[e] = T[jc + 8 + e][dr]; }
    _Float16* dst = vt + (((size_t)bb * HEADS + h) * 64 + dr) * NTOK + j0 + jc;
    *(f16x8*)dst = o0;
    *(f16x8*)(dst + 8) = o1;
}

// ---------------------------------------------------------------------------
// Flash attention v3b: as v3 but the bias register double-buffer is STATICALLY
// indexed (bcur/bnext + copy) — v3's bfr[buf] runtime index sent it to scratch
// (257 MB spill writes, 21x regression). LDS = 48 KB -> 3 blocks/CU.
// ---------------------------------------------------------------------------
__global__ __launch_bounds__(256, 3)
void attn_f16_v3(const _Float16* __restrict__ qkv, const _Float16* __restrict__ vt,
                 const _Float16* __restrict__ biasT, _Float16* __restrict__ out) {
    __shared__ _Float16 Ks[2][64 * 64];   // [j][d], swizzled chunks
    __shared__ _Float16 Vs[2][64 * 64];   // [d][j], swizzled chunks
    __shared__ _Float16 Ps[4][32 * 64];   // per-wave P[m][j], swizzled

    const int t    = threadIdx.x;
    const int l    = t & 63;
    const int w    = t >> 6;
    const int quad = l >> 4;
    const int lrow = l & 15;
    const int h    = blockIdx.y;
    const int bb   = blockIdx.z;
    const int i0   = blockIdx.x * 128;
    const int qr0  = i0 + w * 32;          // this wave's 32 query rows

    const size_t tokbase = (size_t)bb * NTOK;

    // Q fragments: A[m = lrow (+16*mt)][k = ksi*32 + quad*8 + e]
    f16x8 aq[2][2];
#pragma unroll
    for (int mt = 0; mt < 2; ++mt)
#pragma unroll
        for (int ksi = 0; ksi < 2; ++ksi)
            aq[mt][ksi] = *(const f16x8*)(qkv + (tokbase + qr0 + mt * 16 + lrow) * QKV_COLS
                                          + h * DHEAD + ksi * 32 + quad * 8);

    f32x4 O[2][4];
    float lpart[2][4];
#pragma unroll
    for (int mt = 0; mt < 2; ++mt)
#pragma unroll
        for (int k = 0; k < 4; ++k) {
            O[mt][k] = (f32x4){0.f, 0.f, 0.f, 0.f};
            lpart[mt][k] = 0.f;
        }

    const int kr  = t >> 3;     // staging row 0..31
    const int ksl = t & 7;      // LDS chunk slot; holds global chunk ksl^(row&7)
    const _Float16* kbase = qkv + tokbase * QKV_COLS + INNER + h * DHEAD;
    const _Float16* vbase = vt + ((size_t)(bb * HEADS + h) * 64) * NTOK;
    // bias rows j, cols i: this thread's i base = i0 + w*32 + mt*16 + quad*4
    const _Float16* bbase = biasT + ((size_t)h << 20) + i0 + w * 32 + quad * 4;

    auto stage = [&](int jt, int buf) {
        const int j0 = jt * 64;
        const int swz = (ksl ^ (kr & 7)) * 8;
        glds16(kbase + (size_t)(j0 + kr) * QKV_COLS + swz,      (char*)Ks[buf] + t * 16);
        glds16(kbase + (size_t)(j0 + 32 + kr) * QKV_COLS + swz, (char*)Ks[buf] + 4096 + t * 16);
        glds16(vbase + (size_t)kr * NTOK + j0 + swz,            (char*)Vs[buf] + t * 16);
        glds16(vbase + (size_t)(32 + kr) * NTOK + j0 + swz,     (char*)Vs[buf] + 4096 + t * 16);
    };

    // bias double-buffer: STATIC indexing only (dynamic index -> scratch spill)
    f16x4 bcur[8], bnext[8];
    auto load_bias = [&](int jt, f16x4* dst) {
#pragma unroll
        for (int mt = 0; mt < 2; ++mt)
#pragma unroll
            for (int jn = 0; jn < 4; ++jn)
                dst[mt * 4 + jn] =
                    *(const f16x4*)(bbase + (size_t)(jt * 64 + jn * 16 + lrow) * 1024 + mt * 16);
    };

    stage(0, 0);
    load_bias(0, bcur);

    _Float16* Pw = Ps[w];

    for (int jt = 0; jt < 16; ++jt) {
        const int buf = jt & 1;
        __syncthreads();                 // staged tile jt ready; prev compute done
        if (jt < 15) { stage(jt + 1, buf ^ 1); load_bias(jt + 1, bnext); }

        // --- S = Q K^T ---
        f32x4 S[2][4];
#pragma unroll
        for (int jn = 0; jn < 4; ++jn) {
            S[0][jn] = (f32x4){0.f, 0.f, 0.f, 0.f};
            S[1][jn] = (f32x4){0.f, 0.f, 0.f, 0.f};
            const int row = jn * 16 + lrow;
#pragma unroll
            for (int ksi = 0; ksi < 2; ++ksi) {
                f16x8 bk = *(const f16x8*)(Ks[buf] + row * 64 + (((ksi * 4 + quad) ^ (row & 7)) * 8));
#pragma unroll
                for (int mt = 0; mt < 2; ++mt)
                    S[mt][jn] = __builtin_amdgcn_mfma_f32_16x16x32_f16(aq[mt][ksi], bk, S[mt][jn], 0, 0, 0);
            }
        }

        // --- p = exp2(qk*scale' + bias') ; partial sums; P write ---
#pragma unroll
        for (int jn = 0; jn < 4; ++jn) {
#pragma unroll
            for (int mt = 0; mt < 2; ++mt) {
                const int mbase = mt * 16 + quad * 4;
                const f16x4 bv4 = bcur[mt * 4 + jn];
#pragma unroll
                for (int r = 0; r < 4; ++r) {
                    float p = EXP2F(fmaf(S[mt][jn][r], SCALE_L2E, (float)bv4[r]));
                    lpart[mt][r] += p;
                    const int mrow = mbase + r;
                    const int col  = jn * 16 + lrow;
                    Pw[mrow * 64 + (((col >> 3) ^ (mrow & 7)) * 8) + (col & 7)] = (_Float16)p;
                }
            }
        }
        asm volatile("" ::: "memory");   // same-wave DS write->read ordering

        // --- O += P @ V ---
#pragma unroll
        for (int ksi = 0; ksi < 2; ++ksi) {
            f16x8 ap[2];
#pragma unroll
            for (int mt = 0; mt < 2; ++mt) {
                const int arow = mt * 16 + lrow;
                ap[mt] = *(const f16x8*)(Pw + arow * 64 + (((ksi * 4 + quad) ^ (arow & 7)) * 8));
            }
#pragma unroll
            for (int dn = 0; dn < 4; ++dn) {
                const int d = dn * 16 + lrow;
                f16x8 bvv = *(const f16x8*)(Vs[buf] + d * 64 + (((ksi * 4 + quad) ^ (d & 7)) * 8));
#pragma unroll
                for (int mt = 0; mt < 2; ++mt)
                    O[mt][dn] = __builtin_amdgcn_mfma_f32_16x16x32_f16(ap[mt], bvv, O[mt][dn], 0, 0, 0);
            }
        }

        // rotate bias buffer (static copies; bnext garbage at jt=15, unused)
#pragma unroll
        for (int i = 0; i < 8; ++i) bcur[i] = bnext[i];
    }

    // --- final l reduction across the 16 lanes holding each row, write out ---
#pragma unroll
    for (int mt = 0; mt < 2; ++mt) {
#pragma unroll
        for (int r = 0; r < 4; ++r) {
            float s = lpart[mt][r];
#pragma unroll
            for (int off = 1; off < 16; off <<= 1)
                s += __shfl_xor(s, off);
            float inv = 1.f / s;
            const int i = qr0 + mt * 16 + quad * 4 + r;
#pragma unroll
            for (int dn = 0; dn < 4; ++dn)
                out[(tokbase + i) * INNER + h * DHEAD + dn * 16 + lrow] =
                    (_Float16)(O[mt][dn][r] * inv);
        }
    }
}

// ---------------------------------------------------------------------------
extern "C" void kernel_launch(void* const* d_in, const int* in_sizes, int n_in,
                              void* d_out, int out_size, void* d_ws, size_t ws_size,
                              hipStream_t stream) {
    const float* x         = (const float*)d_in[0];
    const float* W_qkv     = (const float*)d_in[1];
    const float* rel_table = (const float*)d_in[2];
    const float* W_out     = (const float*)d_in[3];
    const float* b_out     = (const float*)d_in[4];

    _Float16* x_h   = (_Float16*)d_ws;                        // 8,388,608
    _Float16* Wq_t  = x_h + (size_t)BATCH * NTOK * INNER;     // 786,432
    _Float16* Wo_t  = Wq_t + (size_t)INNER * QKV_COLS;        // 262,144
    _Float16* qkv_h = Wo_t + (size_t)INNER * INNER;           // 25,165,824
    _Float16* att_h = qkv_h + (size_t)BATCH * NTOK * QKV_COLS;// 8,388,608
    _Float16* vt_g  = att_h + (size_t)BATCH * NTOK * INNER;   // 8,388,608
    _Float16* biasT = vt_g + (size_t)BATCH * NTOK * INNER;    // 8,388,608

    const int M = BATCH * NTOK;  // 16384

    build_bias<<<HEADS * NTOK * NTOK / 4 / 256, 256, 0, stream>>>(rel_table, biasT);

    convert_inputs<<<(XV + WQ + WO + 255) / 256, 256, 0, stream>>>(
        x, W_qkv, W_out, x_h, Wq_t, Wo_t);

    gemm_f16<true, false><<<dim3(QKV_COLS / 128, M / 128), 256, 0, stream>>>(
        x_h, Wq_t, nullptr, qkv_h, M, QKV_COLS, INNER);

    transpose_v<<<dim3(NTOK / 64, HEADS, BATCH), 256, 0, stream>>>(qkv_h, vt_g);

    attn_f16_v3<<<dim3(NTOK / 128, HEADS, BATCH), 256, 0, stream>>>(
        qkv_h, vt_g, biasT, att_h);

    gemm_f16<false, true><<<dim3(INNER / 128, M / 128), 256, 0, stream>>>(
        att_h, Wo_t, b_out, d_out, M, INNER, INNER);
}

// Round 11
// 239.644 us; speedup vs baseline: 8.2930x; 1.1532x over previous
//
#include <hip/hip_runtime.h>
#include <math.h>

#define BATCH 16
#define NTOK 1024
#define HEADS 8
#define DHEAD 64
#define INNER 512
#define QKV_COLS 1536
// 0.125 * log2(e): p = exp2(qk*SCALE_L2E + bias*log2e)
#define SCALE_L2E 0.1803368801111244f
#define LOG2E 1.4426950408889634f

#if __has_builtin(__builtin_amdgcn_exp2f)
#define EXP2F(x) __builtin_amdgcn_exp2f(x)
#else
#define EXP2F(x) __expf((x) * 0.6931471805599453f)
#endif

typedef _Float16 f16x8 __attribute__((ext_vector_type(8)));
typedef _Float16 f16x4 __attribute__((ext_vector_type(4)));
typedef float f32x4 __attribute__((ext_vector_type(4)));

// async global->LDS, 16B per lane. LDS dest is wave-uniform base + lane*16.
__device__ __forceinline__ void glds16(const void* g, void* l) {
    __builtin_amdgcn_global_load_lds(
        (const __attribute__((address_space(1))) unsigned int*)g,
        (__attribute__((address_space(3))) unsigned int*)l, 16, 0, 0);
}

// ---------------------------------------------------------------------------
// Input conversion: x -> f16; W_qkv, W_out -> transposed f16 (Bt[n][k]).
// ---------------------------------------------------------------------------
#define XV (BATCH * NTOK * INNER / 4)        // 2097152 float4 groups
#define WQ (INNER * QKV_COLS)                // 786432
#define WO (INNER * INNER)                   // 262144

__global__ __launch_bounds__(256)
void convert_inputs(const float* __restrict__ x, const float* __restrict__ Wq,
                    const float* __restrict__ Wo, _Float16* __restrict__ x_h,
                    _Float16* __restrict__ Wq_t, _Float16* __restrict__ Wo_t) {
    int idx = blockIdx.x * 256 + threadIdx.x;
    if (idx < XV) {
        float4 v = ((const float4*)x)[idx];
        f16x4 h;
        h[0] = (_Float16)v.x; h[1] = (_Float16)v.y;
        h[2] = (_Float16)v.z; h[3] = (_Float16)v.w;
        *(f16x4*)(x_h + (size_t)idx * 4) = h;
    } else if (idx < XV + WQ) {
        int i = idx - XV;
        int n = i >> 9, k = i & 511;                 // Wq_t[n][k] = Wq[k][n]
        Wq_t[i] = (_Float16)Wq[k * QKV_COLS + n];
    } else if (idx < XV + WQ + WO) {
        int i = idx - XV - WQ;
        int n = i >> 9, k = i & 511;
        Wo_t[i] = (_Float16)Wo[k * INNER + n];
    }
}

// ---------------------------------------------------------------------------
// f16 MFMA GEMM (m97 structure): C[M,N] = A[M,K] @ Bt[N,K]^T  (+bias).
// ---------------------------------------------------------------------------
template<bool OUT_F16, bool ADD_BIAS>
__global__ __launch_bounds__(256)
void gemm_f16(const _Float16* __restrict__ A, const _Float16* __restrict__ Bt,
              const float* __restrict__ bias, void* __restrict__ Cout,
              int M, int N, int K) {
    __shared__ _Float16 As[128 * 32];
    __shared__ _Float16 Bs[128 * 32];

    const int t    = threadIdx.x;
    const int l    = t & 63;
    const int w    = t >> 6;
    const int wm   = w >> 1;
    const int wn   = w & 1;
    const int quad = l >> 4;
    const int lrow = l & 15;
    const size_t row0 = (size_t)blockIdx.y * 128;
    const size_t col0 = (size_t)blockIdx.x * 128;

    const int srow = t >> 2;
    const int sch  = t & 3;

    f32x4 acc[4][4] = {};

    for (int k0 = 0; k0 < K; k0 += 32) {
        __syncthreads();
        glds16(A + (row0 + srow) * K + k0 + sch * 8,            (char*)As + t * 16);
        glds16(A + (row0 + 64 + srow) * K + k0 + sch * 8,       (char*)As + 4096 + t * 16);
        glds16(Bt + (col0 + srow) * K + k0 + sch * 8,           (char*)Bs + t * 16);
        glds16(Bt + (col0 + 64 + srow) * K + k0 + sch * 8,      (char*)Bs + 4096 + t * 16);
        __syncthreads();

        f16x8 af[4], bf[4];
#pragma unroll
        for (int i = 0; i < 4; ++i)
            af[i] = *(const f16x8*)(As + (wm * 64 + i * 16 + lrow) * 32 + quad * 8);
#pragma unroll
        for (int j = 0; j < 4; ++j)
            bf[j] = *(const f16x8*)(Bs + (wn * 64 + j * 16 + lrow) * 32 + quad * 8);
#pragma unroll
        for (int i = 0; i < 4; ++i)
#pragma unroll
            for (int j = 0; j < 4; ++j)
                acc[i][j] = __builtin_amdgcn_mfma_f32_16x16x32_f16(af[i], bf[j], acc[i][j], 0, 0, 0);
    }

#pragma unroll
    for (int i = 0; i < 4; ++i) {
#pragma unroll
        for (int j = 0; j < 4; ++j) {
            size_t r = row0 + wm * 64 + i * 16 + quad * 4;
            size_t c = col0 + wn * 64 + j * 16 + lrow;
#pragma unroll
            for (int reg = 0; reg < 4; ++reg) {
                float v = acc[i][j][reg];
                if (OUT_F16) {
                    ((_Float16*)Cout)[(r + reg) * N + c] = (_Float16)v;
                } else {
                    if (ADD_BIAS) v += bias[c];
                    ((float*)Cout)[(r + reg) * N + c] = v;
                }
            }
        }
    }
}

// ---------------------------------------------------------------------------
// V pre-transpose: vt[b][h][d][n] = qkv[b*N+n][2*INNER + h*64 + d].
// ---------------------------------------------------------------------------
__global__ __launch_bounds__(256)
void transpose_v(const _Float16* __restrict__ qkv, _Float16* __restrict__ vt) {
    __shared__ _Float16 T[64][72];
    const int t  = threadIdx.x;
    const int j0 = blockIdx.x * 64;
    const int h  = blockIdx.y, bb = blockIdx.z;
    const int jr = t >> 2;
    const int dc = (t & 3) * 16;
    const _Float16* src = qkv + ((size_t)bb * NTOK + j0 + jr) * QKV_COLS + 2 * INNER + h * DHEAD + dc;
    f16x8 v0 = *(const f16x8*)src;
    f16x8 v1 = *(const f16x8*)(src + 8);
#pragma unroll
    for (int e = 0; e < 8; ++e) { T[jr][dc + e] = v0[e]; T[jr][dc + 8 + e] = v1[e]; }
    __syncthreads();
    const int dr = t >> 2;
    const int jc = (t & 3) * 16;
    f16x8 o0, o1;
#pragma unroll
    for (int e = 0; e < 8; ++e) { o0[e] = T[jc + e][dr]; o1[e] = T[jc + 8 + e][dr]; }
    _Float16* dst = vt + (((size_t)bb * HEADS + h) * 64 + dr) * NTOK + j0 + jc;
    *(f16x8*)dst = o0;
    *(f16x8*)(dst + 8) = o1;
}

// ---------------------------------------------------------------------------
// Flash attention v4: round-4 v2 structure (measured 88.5us) + two fixes to
// its measured VALU hotspot: (a) bias gather vectorized — one idxbase per
// (mt,jn), 4 CONSECUTIVE f32 LDS reads (i never crosses a 32-boundary within
// a quad group; iy is wave-constant) -> compiler emits ds_read2_b32 pairs;
// (b) biasS pre-scaled by log2e, scale folded into fma -> exp2 direct.
// LDS: Ks 16K + Vs 16K + Ps 16K + biasS 15.9K ~= 64K -> 2 blocks/CU.
// ---------------------------------------------------------------------------
__global__ __launch_bounds__(256)
void attn_f16_v4(const _Float16* __restrict__ qkv, const _Float16* __restrict__ vt,
                 const float* __restrict__ rel_table, _Float16* __restrict__ out) {
    __shared__ _Float16 Ks[2][64 * 64];   // [j][d], swizzled chunks
    __shared__ _Float16 Vs[2][64 * 64];   // [d][j], swizzled chunks
    __shared__ _Float16 Ps[4][32 * 64];   // per-wave P[m][j], swizzled
    __shared__ float biasS[3969];         // this head's bias column * log2e

    const int t    = threadIdx.x;
    const int l    = t & 63;
    const int w    = t >> 6;
    const int quad = l >> 4;
    const int lrow = l & 15;
    const int h    = blockIdx.y;
    const int bb   = blockIdx.z;
    const int i0   = blockIdx.x * 128;
    const int qr0  = i0 + w * 32;          // this wave's 32 query rows (32-aligned)

    for (int idx = t; idx < 3969; idx += 256)
        biasS[idx] = rel_table[idx * HEADS + h] * LOG2E;

    const size_t tokbase = (size_t)bb * NTOK;

    // Q fragments: A[m = lrow (+16*mt)][k = ksi*32 + quad*8 + e]
    f16x8 aq[2][2];
#pragma unroll
    for (int mt = 0; mt < 2; ++mt)
#pragma unroll
        for (int ksi = 0; ksi < 2; ++ksi)
            aq[mt][ksi] = *(const f16x8*)(qkv + (tokbase + qr0 + mt * 16 + lrow) * QKV_COLS
                                          + h * DHEAD + ksi * 32 + quad * 8);

    f32x4 O[2][4];
    float lpart[2][4];
#pragma unroll
    for (int mt = 0; mt < 2; ++mt)
#pragma unroll
        for (int k = 0; k < 4; ++k) {
            O[mt][k] = (f32x4){0.f, 0.f, 0.f, 0.f};
            lpart[mt][k] = 0.f;
        }

    // bias geometry: i = qr0 + mt*16 + quad*4 + r. Since qr0 is 32-aligned and
    // mt*16+quad*4+r <= 31, iy = qr0>>5 is wave-constant and ix = mt*16+quad*4+r.
    const int iyc = qr0 >> 5;
    const int ixb0 = quad * 4;             // mt=0 ix base
    const int ixb1 = 16 + quad * 4;        // mt=1 ix base

    const int kr  = t >> 3;     // staging row 0..31
    const int ksl = t & 7;      // LDS chunk slot; holds global chunk ksl^(row&7)
    const _Float16* kbase = qkv + tokbase * QKV_COLS + INNER + h * DHEAD;
    const _Float16* vbase = vt + ((size_t)(bb * HEADS + h) * 64) * NTOK;

    auto stage = [&](int jt, int buf) {
        const int j0 = jt * 64;
        const int swz = (ksl ^ (kr & 7)) * 8;
        glds16(kbase + (size_t)(j0 + kr) * QKV_COLS + swz,      (char*)Ks[buf] + t * 16);
        glds16(kbase + (size_t)(j0 + 32 + kr) * QKV_COLS + swz, (char*)Ks[buf] + 4096 + t * 16);
        glds16(vbase + (size_t)kr * NTOK + j0 + swz,            (char*)Vs[buf] + t * 16);
        glds16(vbase + (size_t)(32 + kr) * NTOK + j0 + swz,     (char*)Vs[buf] + 4096 + t * 16);
    };

    stage(0, 0);

    _Float16* Pw = Ps[w];

    for (int jt = 0; jt < 16; ++jt) {
        const int buf = jt & 1;
        __syncthreads();                 // staged tile jt ready; prev compute done
        if (jt < 15) stage(jt + 1, buf ^ 1);

        const int j0 = jt * 64;

        // --- S = Q K^T ---
        f32x4 S[2][4];
#pragma unroll
        for (int jn = 0; jn < 4; ++jn) {
            S[0][jn] = (f32x4){0.f, 0.f, 0.f, 0.f};
            S[1][jn] = (f32x4){0.f, 0.f, 0.f, 0.f};
            const int row = jn * 16 + lrow;
#pragma unroll
            for (int ksi = 0; ksi < 2; ++ksi) {
                f16x8 bk = *(const f16x8*)(Ks[buf] + row * 64 + (((ksi * 4 + quad) ^ (row & 7)) * 8));
#pragma unroll
                for (int mt = 0; mt < 2; ++mt)
                    S[mt][jn] = __builtin_amdgcn_mfma_f32_16x16x32_f16(aq[mt][ksi], bk, S[mt][jn], 0, 0, 0);
            }
        }

        // --- p = exp2(qk*scale' + bias') ; partial sums; P write ---
#pragma unroll
        for (int jn = 0; jn < 4; ++jn) {
            const int j  = j0 + jn * 16 + lrow;
            const int jy = j >> 5, jx = j & 31;
            const int rowoff = (iyc - jy + 31) * 63 - jx + 31;   // + ix gives idx
#pragma unroll
            for (int mt = 0; mt < 2; ++mt) {
                const int idxbase = rowoff + (mt ? ixb1 : ixb0);
                // 4 consecutive f32 LDS reads -> ds_read2_b32 pairs
                float b0 = biasS[idxbase + 0];
                float b1 = biasS[idxbase + 1];
                float b2 = biasS[idxbase + 2];
                float b3 = biasS[idxbase + 3];
                const int mbase = mt * 16 + quad * 4;
                float p0 = EXP2F(fmaf(S[mt][jn][0], SCALE_L2E, b0));
                float p1 = EXP2F(fmaf(S[mt][jn][1], SCALE_L2E, b1));
                float p2 = EXP2F(fmaf(S[mt][jn][2], SCALE_L2E, b2));
                float p3 = EXP2F(fmaf(S[mt][jn][3], SCALE_L2E, b3));
                lpart[mt][0] += p0; lpart[mt][1] += p1;
                lpart[mt][2] += p2; lpart[mt][3] += p3;
                const int col = jn * 16 + lrow;
                const int csw = ((col >> 3) ^ ((mbase + 0) & 7)) * 8 + (col & 7);
                // rows mbase..mbase+3: swizzle depends on row&7 -> recompute per row
                Pw[(mbase + 0) * 64 + (((col >> 3) ^ ((mbase + 0) & 7)) * 8) + (col & 7)] = (_Float16)p0;
                Pw[(mbase + 1) * 64 + (((col >> 3) ^ ((mbase + 1) & 7)) * 8) + (col & 7)] = (_Float16)p1;
                Pw[(mbase + 2) * 64 + (((col >> 3) ^ ((mbase + 2) & 7)) * 8) + (col & 7)] = (_Float16)p2;
                Pw[(mbase + 3) * 64 + (((col >> 3) ^ ((mbase + 3) & 7)) * 8) + (col & 7)] = (_Float16)p3;
                (void)csw;
            }
        }
        asm volatile("" ::: "memory");   // same-wave DS write->read ordering

        // --- O += P @ V ---
#pragma unroll
        for (int ksi = 0; ksi < 2; ++ksi) {
            f16x8 ap[2];
#pragma unroll
            for (int mt = 0; mt < 2; ++mt) {
                const int arow = mt * 16 + lrow;
                ap[mt] = *(const f16x8*)(Pw + arow * 64 + (((ksi * 4 + quad) ^ (arow & 7)) * 8));
            }
#pragma unroll
            for (int dn = 0; dn < 4; ++dn) {
                const int d = dn * 16 + lrow;
                f16x8 bvv = *(const f16x8*)(Vs[buf] + d * 64 + (((ksi * 4 + quad) ^ (d & 7)) * 8));
#pragma unroll
                for (int mt = 0; mt < 2; ++mt)
                    O[mt][dn] = __builtin_amdgcn_mfma_f32_16x16x32_f16(ap[mt], bvv, O[mt][dn], 0, 0, 0);
            }
        }
    }

    // --- final l reduction across the 16 lanes holding each row, write out ---
#pragma unroll
    for (int mt = 0; mt < 2; ++mt) {
#pragma unroll
        for (int r = 0; r < 4; ++r) {
            float s = lpart[mt][r];
#pragma unroll
            for (int off = 1; off < 16; off <<= 1)
                s += __shfl_xor(s, off);
            float inv = 1.f / s;
            const int i = qr0 + mt * 16 + quad * 4 + r;
#pragma unroll
            for (int dn = 0; dn < 4; ++dn)
                out[(tokbase + i) * INNER + h * DHEAD + dn * 16 + lrow] =
                    (_Float16)(O[mt][dn][r] * inv);
        }
    }
}

// ---------------------------------------------------------------------------
extern "C" void kernel_launch(void* const* d_in, const int* in_sizes, int n_in,
                              void* d_out, int out_size, void* d_ws, size_t ws_size,
                              hipStream_t stream) {
    const float* x         = (const float*)d_in[0];
    const float* W_qkv     = (const float*)d_in[1];
    const float* rel_table = (const float*)d_in[2];
    const float* W_out     = (const float*)d_in[3];
    const float* b_out     = (const float*)d_in[4];

    _Float16* x_h   = (_Float16*)d_ws;                        // 8,388,608
    _Float16* Wq_t  = x_h + (size_t)BATCH * NTOK * INNER;     // 786,432
    _Float16* Wo_t  = Wq_t + (size_t)INNER * QKV_COLS;        // 262,144
    _Float16* qkv_h = Wo_t + (size_t)INNER * INNER;           // 25,165,824
    _Float16* att_h = qkv_h + (size_t)BATCH * NTOK * QKV_COLS;// 8,388,608
    _Float16* vt_g  = att_h + (size_t)BATCH * NTOK * INNER;   // 8,388,608

    const int M = BATCH * NTOK;  // 16384

    convert_inputs<<<(XV + WQ + WO + 255) / 256, 256, 0, stream>>>(
        x, W_qkv, W_out, x_h, Wq_t, Wo_t);

    gemm_f16<true, false><<<dim3(QKV_COLS / 128, M / 128), 256, 0, stream>>>(
        x_h, Wq_t, nullptr, qkv_h, M, QKV_COLS, INNER);

    transpose_v<<<dim3(NTOK / 64, HEADS, BATCH), 256, 0, stream>>>(qkv_h, vt_g);

    attn_f16_v4<<<dim3(NTOK / 128, HEADS, BATCH), 256, 0, stream>>>(
        qkv_h, vt_g, rel_table, att_h);

    gemm_f16<false, true><<<dim3(INNER / 128, M / 128), 256, 0, stream>>>(
        att_h, Wo_t, b_out, d_out, M, INNER, INNER);
}